// Round 6
// baseline (544.339 us; speedup 1.0000x reference)
//
#include <hip/hip_runtime.h>

typedef unsigned short u16;
typedef __attribute__((ext_vector_type(8))) short bf16x8;
typedef __attribute__((ext_vector_type(4))) float f32x4;

constexpr int DM = 1024;   // d_model
constexpr int NH = 16;     // n_head
constexpr int DH = 64;     // d_head
constexpr int QL = 1024;   // qlen
constexpr int ML = 512;    // mlen
constexpr int KL = 1536;   // klen = qlen + mlen
constexpr int RL = 2560;   // rlen = qlen + klen
constexpr int BS = 4;      // batch
constexpr int JT = KL / 64;  // 24 j-tiles of 64
constexpr float SCALE = 0.125f;  // 1/sqrt(64)

static __device__ __forceinline__ u16 f2bf(float f) {
    unsigned u = __float_as_uint(f);
    u += 0x7fffu + ((u >> 16) & 1u);   // RNE
    return (u16)(u >> 16);
}

// async global->LDS DMA, 16B per lane. LDS dest = wave-uniform base + lane*16.
static __device__ __forceinline__ void glds16(const u16* g, u16* l) {
    __builtin_amdgcn_global_load_lds(
        (const __attribute__((address_space(1))) unsigned int*)g,
        (__attribute__((address_space(3))) unsigned int*)l,
        16, 0, 0);
}

// ---------------------------------------------------------------------------
// Fused prep (1 launch): blocks [0,17408) fp32->bf16 convert of cat/r/Wo;
// [17408,18432) W transpose-convert; [18432,43008) mask/seg bit-pack.
// ---------------------------------------------------------------------------
__global__ __launch_bounds__(256) void prep_kernel(
    const float* __restrict__ mems, const float* __restrict__ h,
    const float* __restrict__ r, const float* __restrict__ Wo,
    const float* __restrict__ mask, const float* __restrict__ segm,
    const float* __restrict__ Wq, const float* __restrict__ Wk,
    const float* __restrict__ Wv, const float* __restrict__ Wr,
    u16* __restrict__ catb, u16* __restrict__ rb, u16* __restrict__ wob,
    u16* __restrict__ WqT, u16* __restrict__ WkT,
    u16* __restrict__ WvT, u16* __restrict__ WrT,
    ulonglong2* __restrict__ pk)
{
    __shared__ float smem[64 * 65];
    const int id = blockIdx.x;
    const int t = threadIdx.x;

    if (id < 17408) {        // ---- convert ----
        const long C0 = (long)ML * BS * DM;
        const long C1 = (long)KL * BS * DM;
        const long C2 = C1 + (long)RL * BS * DM;
        long g = ((long)id * 256 + t) * 4;
        const float* src; u16* dst;
        if (g < C0)      { src = mems + g;        dst = catb + g; }
        else if (g < C1) { src = h + (g - C0);    dst = catb + g; }
        else if (g < C2) { src = r + (g - C1);    dst = rb + (g - C1); }
        else             { src = Wo + (g - C2);   dst = wob + (g - C2); }
        float4 v = *(const float4*)src;
        unsigned lo = (unsigned)f2bf(v.x) | ((unsigned)f2bf(v.y) << 16);
        unsigned hi = (unsigned)f2bf(v.z) | ((unsigned)f2bf(v.w) << 16);
        *(uint2*)dst = make_uint2(lo, hi);
        return;
    }
    if (id < 18432) {        // ---- W transpose ----
        float (*tile)[65] = (float(*)[65])smem;
        const int local = id - 17408;
        const float* W; u16* WT;
        switch (local >> 8) {
            case 0:  W = Wq; WT = WqT; break;
            case 1:  W = Wk; WT = WkT; break;
            case 2:  W = Wv; WT = WvT; break;
            default: W = Wr; WT = WrT; break;
        }
        const int k0 = (local & 15) * 64, n0 = ((local >> 4) & 15) * 64;
        const int tr = t >> 6, tc = t & 63;
        #pragma unroll
        for (int rr = 0; rr < 16; rr++) {
            int rw = tr + rr * 4;
            tile[rw][tc] = W[(size_t)(k0 + rw) * DM + n0 + tc];
        }
        __syncthreads();
        #pragma unroll
        for (int rr = 0; rr < 16; rr++) {
            int n = tr + rr * 4;
            WT[(size_t)(n0 + n) * DM + k0 + tc] = f2bf(tile[tc][n]);
        }
        return;
    }
    // ---- pack mask/seg bits ----
    {
        float* mk = smem;
        float* sg = smem + 256;
        const int local = id - 18432;
        const int i = local / JT, jt = local - i * JT;
        const size_t base = ((size_t)i * KL + jt * 64) * BS;   // float idx (j*4+b)
        mk[t] = mask[base + t];
        float2 s2 = ((const float2*)(segm + base * 2))[t];
        sg[t] = s2.y;
        __syncthreads();
        const int b = t >> 6, lane = t & 63;
        const unsigned long long mb = __ballot(mk[lane * 4 + b] > 0.5f);
        const unsigned long long sb = __ballot(sg[lane * 4 + b] > 0.5f);
        if (lane == 0) {
            ulonglong2 v; v.x = mb; v.y = sb;
            pk[((size_t)b * QL + i) * JT + jt] = v;
        }
    }
}

// ---------------------------------------------------------------------------
// Fused projection uber-GEMM: all 4 projections (q/k/v/kr) in ONE launch.
// m97-style glds staging, 128x128 tile, BK=32.
// MODE 1: fp32 scatter [b][n][seq][d].  MODE 2: bf16 scatter [b][n][seq][d].
// ---------------------------------------------------------------------------
__global__ __launch_bounds__(256) void proj_kernel(
    const u16* __restrict__ hb, const u16* __restrict__ catb,
    const u16* __restrict__ rb,
    const u16* __restrict__ WqT, const u16* __restrict__ WkT,
    const u16* __restrict__ WvT, const u16* __restrict__ WrT,
    float* __restrict__ q_s, u16* __restrict__ k_s,
    u16* __restrict__ v_s, u16* __restrict__ kr_s)
{
    __shared__ u16 a_lds[128][32];   // unpadded: required by global_load_lds
    __shared__ u16 b_lds[128][32];
    const int id = blockIdx.x;
    const u16 *A, *B; void* C; int SEQ, MODE, local;
    if (id < 256)       { A = hb;   B = WqT; C = q_s;  SEQ = QL; MODE = 1; local = id; }
    else if (id < 640)  { A = catb; B = WkT; C = k_s;  SEQ = KL; MODE = 2; local = id - 256; }
    else if (id < 1024) { A = catb; B = WvT; C = v_s;  SEQ = KL; MODE = 2; local = id - 640; }
    else                { A = rb;   B = WrT; C = kr_s; SEQ = RL; MODE = 2; local = id - 1024; }
    const int bm = local >> 3, bnn = local & 7;

    const int t = threadIdx.x;
    const int w = t >> 6, lane = t & 63, l15 = lane & 15, q4 = lane >> 4;
    const int wm = (w >> 1) * 64, wn = (w & 1) * 64;
    const int srow = w * 32 + (lane >> 2);
    const int scol = (lane & 3) * 8;
    const u16* Ab = A + (size_t)(bm * 128 + srow) * DM + scol;
    const u16* Bb = B + (size_t)(bnn * 128 + srow) * DM + scol;
    u16* a_dst = &a_lds[w * 32][0];
    u16* b_dst = &b_lds[w * 32][0];

    f32x4 acc[4][4] = {};

    for (int k0 = 0; k0 < DM; k0 += 32) {
        __syncthreads();
        glds16(Ab + k0,           a_dst);
        glds16(Ab + k0 + 16 * DM, a_dst + 16 * 32);
        glds16(Bb + k0,           b_dst);
        glds16(Bb + k0 + 16 * DM, b_dst + 16 * 32);
        __syncthreads();
        bf16x8 af[4], bf[4];
        #pragma unroll
        for (int rt = 0; rt < 4; rt++)
            af[rt] = *(const bf16x8*)&a_lds[wm + rt * 16 + l15][q4 * 8];
        #pragma unroll
        for (int ct = 0; ct < 4; ct++)
            bf[ct] = *(const bf16x8*)&b_lds[wn + ct * 16 + l15][q4 * 8];
        #pragma unroll
        for (int rt = 0; rt < 4; rt++)
            #pragma unroll
            for (int ct = 0; ct < 4; ct++)
                acc[rt][ct] = __builtin_amdgcn_mfma_f32_16x16x32_bf16(
                    af[rt], bf[ct], acc[rt][ct], 0, 0, 0);
    }

    #pragma unroll
    for (int rt = 0; rt < 4; rt++)
      #pragma unroll
      for (int ct = 0; ct < 4; ct++)
        #pragma unroll
        for (int rg = 0; rg < 4; rg++) {
            const int R = bm * 128 + wm + rt * 16 + q4 * 4 + rg;   // seq*4+b
            const int Cc = bnn * 128 + wn + ct * 16 + l15;         // n*64+d
            const float v = acc[rt][ct][rg];
            const int sq = R >> 2, bb = R & 3, hn = Cc >> 6, dd = Cc & 63;
            const size_t idx = ((size_t)(bb * NH + hn) * SEQ + sq) * DH + dd;
            if (MODE == 1) ((float*)C)[idx] = v;
            else           ((u16*)C)[idx]  = f2bf(v);
        }
}

// ---------------------------------------------------------------------------
// v [b][n][j][d] -> vt [b][n][d][j], 64x64 LDS tile transpose.
// ---------------------------------------------------------------------------
__global__ __launch_bounds__(256) void vtrans_kernel(
    const u16* __restrict__ v_s, u16* __restrict__ vt_s)
{
    __shared__ u16 tl[64][72];
    const int j0 = blockIdx.x * 64;
    const int bn = blockIdx.y;
    const u16* vin = v_s + (size_t)bn * KL * DH;
    u16* vout = vt_s + (size_t)bn * DH * KL;
    const int t = threadIdx.x;
    const int r = t >> 3, c8 = (t & 7) * 8;
    #pragma unroll
    for (int it = 0; it < 64; it += 32)
        *(uint4*)&tl[r + it][c8] = *(const uint4*)(vin + (size_t)(j0 + r + it) * DH + c8);
    __syncthreads();
    #pragma unroll
    for (int it = 0; it < 64; it += 32) {
        const int d = r + it;
        u16 tmp[8];
        #pragma unroll
        for (int jj = 0; jj < 8; jj++) tmp[jj] = tl[c8 + jj][d];
        *(uint4*)&vout[(size_t)d * KL + j0 + c8] = *(const uint4*)tmp;
    }
}

// ---------------------------------------------------------------------------
// Out-projection GEMM (fp32 row-major out), m97-style staging.
// ---------------------------------------------------------------------------
__global__ __launch_bounds__(256) void ogemm_kernel(
    const u16* __restrict__ A, const u16* __restrict__ B,
    float* __restrict__ Cout)
{
    __shared__ u16 a_lds[128][32];
    __shared__ u16 b_lds[128][32];
    const int bm = blockIdx.x, bnn = blockIdx.y;
    const int t = threadIdx.x;
    const int w = t >> 6, lane = t & 63, l15 = lane & 15, q4 = lane >> 4;
    const int wm = (w >> 1) * 64, wn = (w & 1) * 64;
    const int srow = w * 32 + (lane >> 2);
    const int scol = (lane & 3) * 8;
    const u16* Ab = A + (size_t)(bm * 128 + srow) * DM + scol;
    const u16* Bb = B + (size_t)(bnn * 128 + srow) * DM + scol;
    u16* a_dst = &a_lds[w * 32][0];
    u16* b_dst = &b_lds[w * 32][0];

    f32x4 acc[4][4] = {};

    for (int k0 = 0; k0 < DM; k0 += 32) {
        __syncthreads();
        glds16(Ab + k0,           a_dst);
        glds16(Ab + k0 + 16 * DM, a_dst + 16 * 32);
        glds16(Bb + k0,           b_dst);
        glds16(Bb + k0 + 16 * DM, b_dst + 16 * 32);
        __syncthreads();
        bf16x8 af[4], bf[4];
        #pragma unroll
        for (int rt = 0; rt < 4; rt++)
            af[rt] = *(const bf16x8*)&a_lds[wm + rt * 16 + l15][q4 * 8];
        #pragma unroll
        for (int ct = 0; ct < 4; ct++)
            bf[ct] = *(const bf16x8*)&b_lds[wn + ct * 16 + l15][q4 * 8];
        #pragma unroll
        for (int rt = 0; rt < 4; rt++)
            #pragma unroll
            for (int ct = 0; ct < 4; ct++)
                acc[rt][ct] = __builtin_amdgcn_mfma_f32_16x16x32_bf16(
                    af[rt], bf[ct], acc[rt][ct], 0, 0, 0);
    }

    #pragma unroll
    for (int rt = 0; rt < 4; rt++)
      #pragma unroll
      for (int ct = 0; ct < 4; ct++)
        #pragma unroll
        for (int rg = 0; rg < 4; rg++) {
            const int R = bm * 128 + wm + rt * 16 + q4 * 4 + rg;
            const int C = bnn * 128 + wn + ct * 16 + l15;
            Cout[(size_t)R * DM + C] = acc[rt][ct][rg];
        }
}

// ---------------------------------------------------------------------------
// Fused relative attention.  grid = (16 i-tiles, 64 bn), 4 waves x 16 q-rows.
// All tiles staged via global_load_lds. P-scratch OVERLAYS krl (first 9.2 KB)
// -> LDS 33.3 KB -> 4 blocks/CU resident (grid is exactly 4/CU: no tail
// round). 3 barriers/tile: A) prev PV done -> stage; B) vmcnt drained ->
// ac/bd MFMAs read k2/krl; C) all krl reads done -> softmax writes P into
// krl space -> PV. bd band extract via shfl; softmax w/o running max.
// ---------------------------------------------------------------------------
__global__ __launch_bounds__(256, 4) void attn_kernel(
    const float* __restrict__ q_s, const u16* __restrict__ k_s,
    const u16* __restrict__ vt_s, const u16* __restrict__ kr_s,
    const ulonglong2* __restrict__ pk,
    const float* __restrict__ rwb, const float* __restrict__ rrb,
    const float* __restrict__ rsb, const float* __restrict__ seg_embed,
    u16* __restrict__ av_s)
{
    __shared__ u16 k2[2][64][32];    // [kk-half][j][d32]  (unpadded for glds)
    __shared__ u16 vt2[2][64][32];   // [kk-half][d][j32]
    __shared__ u16 krl[128][64];     // kr rows, seg-swizzled; P overlays head
    __shared__ float e_lds[2][64];
    u16 (*p_lds)[16][72] = (u16(*)[16][72])&krl[0][0];   // 9216 B <= 16384 B

    const int itile = blockIdx.x;
    const int bn = blockIdx.y;           // b*16 + n
    const int b = bn >> 4, n = bn & 15;
    const int t = threadIdx.x;
    const int w = t >> 6, lane = t & 63, l15 = lane & 15, q4 = lane >> 4;
    const int i0 = itile * 64;
    const int ib = i0 + w * 16;

    const float* q_bn = q_s + (size_t)bn * QL * DH;
    const u16* k_bn   = k_s  + (size_t)bn * KL * DH;
    const u16* vt_bn  = vt_s + (size_t)bn * DH * KL;
    const u16* kr_bn  = kr_s + (size_t)bn * RL * DH;
    const ulonglong2* pk_b = pk + (size_t)b * QL * JT;

    // ef pre-dots: e_lds[s][block_row] = (q + r_s_bias) . seg_embed[s,n]
    if (t < 128) {
        const int rr = t >> 1, s = t & 1;
        const float* qrow = q_bn + (size_t)(i0 + rr) * DH;
        const float* se = seg_embed + (s * NH + n) * DH;
        const float* bias = rsb + n * DH;
        float acc = 0.f;
        #pragma unroll 16
        for (int d = 0; d < DH; d++) acc += (qrow[d] + bias[d]) * se[d];
        e_lds[s][rr] = acc;
    }

    // q fragments (A-layout: row = l15, k = kk*32 + q4*8 + j), biases folded
    bf16x8 qw[2], qr[2];
    {
        const float* qrow = q_bn + (size_t)(ib + l15) * DH;
        const float* bw = rwb + n * DH;
        const float* br = rrb + n * DH;
        #pragma unroll
        for (int kk = 0; kk < 2; kk++) {
            const int dbase = kk * 32 + q4 * 8;
            #pragma unroll
            for (int j = 0; j < 8; j++) {
                float qv = qrow[dbase + j];
                qw[kk][j] = (short)f2bf(qv + bw[dbase + j]);
                qr[kk][j] = (short)f2bf(qv + br[dbase + j]);
            }
        }
    }

    // k/vt staging lane coords (16 rows per glds, 4 lanes x 16B per row)
    const int srow = lane >> 2;
    const int sseg = (lane & 3) * 8;
    const u16* kg = k_bn  + (size_t)(w * 16 + srow) * DH + sseg;
    const u16* vg = vt_bn + (size_t)(w * 16 + srow) * KL + sseg;
    u16* kd0 = &k2[0][w * 16][0];
    u16* kd1 = &k2[1][w * 16][0];
    u16* vd0 = &vt2[0][w * 16][0];
    u16* vd1 = &vt2[1][w * 16][0];

    // kr staging coords: wave stages rows [w*32, w*32+32) of krl, 4 glds of
    // 8 rows each; seg-XOR swizzle s^(r&7) keeps bd reads at banking floor.
    const int krow = lane >> 3;
    const int ksrcseg = (lane & 7) ^ krow;
    u16* krd = &krl[w * 32][0];

    f32x4 o[4] = {};
    float l_r[4] = {0.f, 0.f, 0.f, 0.f};

    // bd read coords: window wc row = 48 - w*16 + wc*16 + l15; (row&7)==l15&7
    const int lrb = 48 - w * 16 + l15;
    const int sA = ((q4)     ^ (l15 & 7)) * 8;   // kk=0 seg offset (elems)
    const int sB = ((q4 + 4) ^ (l15 & 7)) * 8;   // kk=1

    for (int jt = 0; jt < JT; jt++) {
        const int j0 = jt * 64;
        const int Pbase = j0 + QL - i0 - 63;     // >= 1
        __syncthreads();   // A: prev-tile PV/p reads done (e_lds ready @jt=0)
        glds16(kg + (size_t)j0 * DH,      kd0);
        glds16(kg + (size_t)j0 * DH + 32, kd1);
        glds16(vg + j0,                   vd0);
        glds16(vg + j0 + 32,              vd1);
        {
            const u16* krg = kr_bn + (size_t)(Pbase + w * 32 + krow) * DH + ksrcseg * 8;
            #pragma unroll
            for (int m = 0; m < 4; m++)
                glds16(krg + (size_t)m * 8 * DH, krd + m * 8 * 64);
        }
        ulonglong2 mp[4];
        #pragma unroll
        for (int rg = 0; rg < 4; rg++)
            mp[rg] = pk_b[(size_t)(ib + q4 * 4 + rg) * JT + jt];
        __syncthreads();   // B: drains vmcnt -> all LDS tiles ready

        // ---- ac = (q + r_w_bias) . K^T ----
        f32x4 sac[4] = {};
        #pragma unroll
        for (int ct = 0; ct < 4; ct++) {
            bf16x8 kb0 = *(const bf16x8*)&k2[0][ct * 16 + l15][q4 * 8];
            bf16x8 kb1 = *(const bf16x8*)&k2[1][ct * 16 + l15][q4 * 8];
            sac[ct] = __builtin_amdgcn_mfma_f32_16x16x32_bf16(qw[0], kb0, sac[ct], 0, 0, 0);
            sac[ct] = __builtin_amdgcn_mfma_f32_16x16x32_bf16(qw[1], kb1, sac[ct], 0, 0, 0);
        }

        // ---- bd window MFMAs (B-frags from swizzled krl) ----
        f32x4 bacc[5] = {};
        #pragma unroll
        for (int wc = 0; wc < 5; wc++) {
            bf16x8 b0 = *(const bf16x8*)&krl[lrb + wc * 16][sA];
            bf16x8 b1 = *(const bf16x8*)&krl[lrb + wc * 16][sB];
            bacc[wc] = __builtin_amdgcn_mfma_f32_16x16x32_bf16(qr[0], b0, bacc[wc], 0, 0, 0);
            bacc[wc] = __builtin_amdgcn_mfma_f32_16x16x32_bf16(qr[1], b1, bacc[wc], 0, 0, 0);
        }

        __syncthreads();   // C: all waves' krl reads done -> safe to write P

        // ---- band extract (shfl) + scores + exp + P-store + row-sum ----
        #pragma unroll
        for (int rg = 0; rg < 4; rg++) {
            const int row = q4 * 4 + rg;
            const int v = l15 + 15 - row;          // in [0,30]
            const int srcl = (q4 << 4) | (v & 15);
            float sh[5];
            #pragma unroll
            for (int w5 = 0; w5 < 5; w5++)
                sh[w5] = __shfl(bacc[w5][rg], srcl, 64);
            const float e0 = e_lds[0][w * 16 + row];
            const float e1 = e_lds[1][w * 16 + row];
            float s0 = 0.f;
            #pragma unroll
            for (int ct = 0; ct < 4; ct++) {
                const float bd = (v < 16) ? sh[ct] : sh[ct + 1];
                const int bit = ct * 16 + l15;
                const float ef = ((mp[rg].y >> bit) & 1ull) ? e1 : e0;
                float s = (sac[ct][rg] + bd + ef) * SCALE;
                s = ((mp[rg].x >> bit) & 1ull) ? -1e30f : s;
                const float p = __expf(s);
                p_lds[w][row][ct * 16 + l15] = f2bf(p);
                s0 += p;
            }
            #pragma unroll
            for (int off = 1; off < 16; off <<= 1)
                s0 += __shfl_xor(s0, off, 64);
            l_r[rg] += s0;
        }

        // ---- PV MFMA (P read back in A-layout, same wave) ----
        #pragma unroll
        for (int kk = 0; kk < 2; kk++) {
            bf16x8 pf = *(const bf16x8*)&p_lds[w][l15][kk * 32 + q4 * 8];
            #pragma unroll
            for (int dt = 0; dt < 4; dt++) {
                bf16x8 vf = *(const bf16x8*)&vt2[kk][dt * 16 + l15][q4 * 8];
                o[dt] = __builtin_amdgcn_mfma_f32_16x16x32_bf16(pf, vf, o[dt], 0, 0, 0);
            }
        }
    }

    // ---- epilogue: normalize, write attn_vec bf16 [(i*4+b)][n*64+d] ----
    #pragma unroll
    for (int dt = 0; dt < 4; dt++)
        #pragma unroll
        for (int rg = 0; rg < 4; rg++) {
            const int row = q4 * 4 + rg;
            const int ii = ib + row;
            const int d = dt * 16 + l15;
            const float v = o[dt][rg] / l_r[rg];
            av_s[(size_t)(ii * BS + b) * DM + n * DH + d] = f2bf(v);
        }
}

// ---------------------------------------------------------------------------
// Residual + LayerNorm: out = LN(ao + h) * gamma + beta. One block per row.
// ---------------------------------------------------------------------------
__global__ __launch_bounds__(256) void ln_kernel(
    const float* __restrict__ ao, const float* __restrict__ h,
    const float* __restrict__ gamma, const float* __restrict__ beta,
    float* __restrict__ out)
{
    __shared__ float red[8];
    const int row = blockIdx.x, t = threadIdx.x;
    const float* a  = ao + (size_t)row * DM;
    const float* hh = h  + (size_t)row * DM;
    float4 av = *(const float4*)(a + t * 4);
    float4 hv = *(const float4*)(hh + t * 4);
    const float x0 = av.x + hv.x, x1 = av.y + hv.y;
    const float x2 = av.z + hv.z, x3 = av.w + hv.w;
    float s = x0 + x1 + x2 + x3;
    float s2 = x0 * x0 + x1 * x1 + x2 * x2 + x3 * x3;
    #pragma unroll
    for (int off = 1; off < 64; off <<= 1) {
        s  += __shfl_xor(s, off, 64);
        s2 += __shfl_xor(s2, off, 64);
    }
    const int w = t >> 6;
    if ((t & 63) == 0) { red[w] = s; red[4 + w] = s2; }
    __syncthreads();
    s  = red[0] + red[1] + red[2] + red[3];
    s2 = red[4] + red[5] + red[6] + red[7];
    const float mu = s * (1.f / DM);
    const float var = s2 * (1.f / DM) - mu * mu;
    const float rstd = rsqrtf(var + 1e-12f);
    float4 g  = *(const float4*)(gamma + t * 4);
    float4 bb = *(const float4*)(beta + t * 4);
    float4 ov;
    ov.x = (x0 - mu) * rstd * g.x + bb.x;
    ov.y = (x1 - mu) * rstd * g.y + bb.y;
    ov.z = (x2 - mu) * rstd * g.z + bb.z;
    ov.w = (x3 - mu) * rstd * g.w + bb.w;
    *(float4*)(out + (size_t)row * DM + t * 4) = ov;
}

// ---------------------------------------------------------------------------
extern "C" void kernel_launch(void* const* d_in, const int* in_sizes, int n_in,
                              void* d_out, int out_size, void* d_ws, size_t ws_size,
                              hipStream_t stream) {
    (void)in_sizes; (void)n_in; (void)out_size; (void)ws_size;
    const float* h    = (const float*)d_in[0];
    const float* r    = (const float*)d_in[1];
    const float* mems = (const float*)d_in[2];
    const float* mask = (const float*)d_in[3];
    const float* segm = (const float*)d_in[4];
    const float* Wq   = (const float*)d_in[5];
    const float* Wk   = (const float*)d_in[6];
    const float* Wv   = (const float*)d_in[7];
    const float* Wo   = (const float*)d_in[8];
    const float* Wr   = (const float*)d_in[9];
    const float* rwb  = (const float*)d_in[10];
    const float* rrb  = (const float*)d_in[11];
    const float* rsb  = (const float*)d_in[12];
    const float* semb = (const float*)d_in[13];
    const float* gam  = (const float*)d_in[14];
    const float* bet  = (const float*)d_in[15];
    float* out = (float*)d_out;

    char* wsb = (char*)d_ws;
    size_t off = 0;
    auto alloc = [&](size_t bytes) -> void* {
        void* p = wsb + off; off += (bytes + 255) & ~(size_t)255; return p;
    };
    u16* catb = (u16*)alloc((size_t)KL * BS * DM * 2);
    u16* rb   = (u16*)alloc((size_t)RL * BS * DM * 2);
    u16* WqT  = (u16*)alloc((size_t)DM * DM * 2);
    u16* WkT  = (u16*)alloc((size_t)DM * DM * 2);
    u16* WvT  = (u16*)alloc((size_t)DM * DM * 2);
    u16* WrT  = (u16*)alloc((size_t)DM * DM * 2);
    u16* WoB  = (u16*)alloc((size_t)DM * DM * 2);
    float* q_s = (float*)alloc((size_t)BS * NH * QL * DH * 4);
    u16* k_s  = (u16*)alloc((size_t)BS * NH * KL * DH * 2);
    u16* vt_s = (u16*)alloc((size_t)BS * NH * KL * DH * 2);
    u16* kr_s = (u16*)alloc((size_t)BS * NH * RL * DH * 2 + 8192); // tail pad: kr window over-read
    u16* av_s = (u16*)alloc((size_t)QL * BS * DM * 2);
    float* ao_s = (float*)alloc((size_t)QL * BS * DM * 4);
    ulonglong2* pk = (ulonglong2*)alloc((size_t)BS * QL * JT * 16);
    u16* v_s = (u16*)ao_s;   // alias: v_s dead before ao_s is written

    // 1) fused prep: convert + W transpose + mask/seg pack (one launch)
    prep_kernel<<<43008, 256, 0, stream>>>(mems, h, r, Wo, mask, segm,
                                           Wq, Wk, Wv, Wr,
                                           catb, rb, WoB,
                                           WqT, WkT, WvT, WrT, pk);
    // 2) all 4 projections in one launch (hb = h part of catb)
    const u16* hb = catb + (size_t)2048 * DM;
    proj_kernel<<<1664, 256, 0, stream>>>(hb, catb, rb, WqT, WkT, WvT, WrT,
                                          q_s, k_s, v_s, kr_s);
    // 2b) v -> v^T
    vtrans_kernel<<<dim3(JT, 64), 256, 0, stream>>>(v_s, vt_s);
    // 3) fused attention
    attn_kernel<<<dim3(16, 64), 256, 0, stream>>>(q_s, k_s, vt_s, kr_s, pk,
                                                  rwb, rrb, rsb, semb, av_s);
    // 4) output projection + residual layernorm
    ogemm_kernel<<<dim3(32, 8), 256, 0, stream>>>(av_s, WoB, ao_s);
    ln_kernel<<<4096, 256, 0, stream>>>(ao_s, h, gam, bet, out);
}

// Round 7
// 529.959 us; speedup vs baseline: 1.0271x; 1.0271x over previous
//
#include <hip/hip_runtime.h>

typedef unsigned short u16;
typedef __attribute__((ext_vector_type(8))) short bf16x8;
typedef __attribute__((ext_vector_type(4))) float f32x4;

constexpr int DM = 1024;   // d_model
constexpr int NH = 16;     // n_head
constexpr int DH = 64;     // d_head
constexpr int QL = 1024;   // qlen
constexpr int ML = 512;    // mlen
constexpr int KL = 1536;   // klen = qlen + mlen
constexpr int RL = 2560;   // rlen = qlen + klen
constexpr int BS = 4;      // batch
constexpr int JT = KL / 64;  // 24 j-tiles of 64
constexpr float SCALE = 0.125f;  // 1/sqrt(64)

static __device__ __forceinline__ u16 f2bf(float f) {
    unsigned u = __float_as_uint(f);
    u += 0x7fffu + ((u >> 16) & 1u);   // RNE
    return (u16)(u >> 16);
}

// async global->LDS DMA, 16B per lane. LDS dest = wave-uniform base + lane*16.
static __device__ __forceinline__ void glds16(const u16* g, u16* l) {
    __builtin_amdgcn_global_load_lds(
        (const __attribute__((address_space(1))) unsigned int*)g,
        (__attribute__((address_space(3))) unsigned int*)l,
        16, 0, 0);
}

// ---------------------------------------------------------------------------
// Fused prep (1 launch): blocks [0,17408) fp32->bf16 convert of cat/r/Wo;
// [17408,18432) W transpose-convert; [18432,43008) mask/seg bit-pack.
// ---------------------------------------------------------------------------
__global__ __launch_bounds__(256) void prep_kernel(
    const float* __restrict__ mems, const float* __restrict__ h,
    const float* __restrict__ r, const float* __restrict__ Wo,
    const float* __restrict__ mask, const float* __restrict__ segm,
    const float* __restrict__ Wq, const float* __restrict__ Wk,
    const float* __restrict__ Wv, const float* __restrict__ Wr,
    u16* __restrict__ catb, u16* __restrict__ rb, u16* __restrict__ wob,
    u16* __restrict__ WqT, u16* __restrict__ WkT,
    u16* __restrict__ WvT, u16* __restrict__ WrT,
    ulonglong2* __restrict__ pk)
{
    __shared__ float smem[64 * 65];
    const int id = blockIdx.x;
    const int t = threadIdx.x;

    if (id < 17408) {        // ---- convert ----
        const long C0 = (long)ML * BS * DM;
        const long C1 = (long)KL * BS * DM;
        const long C2 = C1 + (long)RL * BS * DM;
        long g = ((long)id * 256 + t) * 4;
        const float* src; u16* dst;
        if (g < C0)      { src = mems + g;        dst = catb + g; }
        else if (g < C1) { src = h + (g - C0);    dst = catb + g; }
        else if (g < C2) { src = r + (g - C1);    dst = rb + (g - C1); }
        else             { src = Wo + (g - C2);   dst = wob + (g - C2); }
        float4 v = *(const float4*)src;
        unsigned lo = (unsigned)f2bf(v.x) | ((unsigned)f2bf(v.y) << 16);
        unsigned hi = (unsigned)f2bf(v.z) | ((unsigned)f2bf(v.w) << 16);
        *(uint2*)dst = make_uint2(lo, hi);
        return;
    }
    if (id < 18432) {        // ---- W transpose ----
        float (*tile)[65] = (float(*)[65])smem;
        const int local = id - 17408;
        const float* W; u16* WT;
        switch (local >> 8) {
            case 0:  W = Wq; WT = WqT; break;
            case 1:  W = Wk; WT = WkT; break;
            case 2:  W = Wv; WT = WvT; break;
            default: W = Wr; WT = WrT; break;
        }
        const int k0 = (local & 15) * 64, n0 = ((local >> 4) & 15) * 64;
        const int tr = t >> 6, tc = t & 63;
        #pragma unroll
        for (int rr = 0; rr < 16; rr++) {
            int rw = tr + rr * 4;
            tile[rw][tc] = W[(size_t)(k0 + rw) * DM + n0 + tc];
        }
        __syncthreads();
        #pragma unroll
        for (int rr = 0; rr < 16; rr++) {
            int n = tr + rr * 4;
            WT[(size_t)(n0 + n) * DM + k0 + tc] = f2bf(tile[tc][n]);
        }
        return;
    }
    // ---- pack mask/seg bits ----
    {
        float* mk = smem;
        float* sg = smem + 256;
        const int local = id - 18432;
        const int i = local / JT, jt = local - i * JT;
        const size_t base = ((size_t)i * KL + jt * 64) * BS;   // float idx (j*4+b)
        mk[t] = mask[base + t];
        float2 s2 = ((const float2*)(segm + base * 2))[t];
        sg[t] = s2.y;
        __syncthreads();
        const int b = t >> 6, lane = t & 63;
        const unsigned long long mb = __ballot(mk[lane * 4 + b] > 0.5f);
        const unsigned long long sb = __ballot(sg[lane * 4 + b] > 0.5f);
        if (lane == 0) {
            ulonglong2 v; v.x = mb; v.y = sb;
            pk[((size_t)b * QL + i) * JT + jt] = v;
        }
    }
}

// ---------------------------------------------------------------------------
// Fused projection uber-GEMM: all 4 projections (q/k/v/kr) in ONE launch.
// m97-style glds staging, 128x128 tile, BK=32.
// MODE 1: fp32 scatter [b][n][seq][d].  MODE 2: bf16 scatter [b][n][seq][d].
// ---------------------------------------------------------------------------
__global__ __launch_bounds__(256) void proj_kernel(
    const u16* __restrict__ hb, const u16* __restrict__ catb,
    const u16* __restrict__ rb,
    const u16* __restrict__ WqT, const u16* __restrict__ WkT,
    const u16* __restrict__ WvT, const u16* __restrict__ WrT,
    float* __restrict__ q_s, u16* __restrict__ k_s,
    u16* __restrict__ v_s, u16* __restrict__ kr_s)
{
    __shared__ u16 a_lds[128][32];   // unpadded: required by global_load_lds
    __shared__ u16 b_lds[128][32];
    const int id = blockIdx.x;
    const u16 *A, *B; void* C; int SEQ, MODE, local;
    if (id < 256)       { A = hb;   B = WqT; C = q_s;  SEQ = QL; MODE = 1; local = id; }
    else if (id < 640)  { A = catb; B = WkT; C = k_s;  SEQ = KL; MODE = 2; local = id - 256; }
    else if (id < 1024) { A = catb; B = WvT; C = v_s;  SEQ = KL; MODE = 2; local = id - 640; }
    else                { A = rb;   B = WrT; C = kr_s; SEQ = RL; MODE = 2; local = id - 1024; }
    const int bm = local >> 3, bnn = local & 7;

    const int t = threadIdx.x;
    const int w = t >> 6, lane = t & 63, l15 = lane & 15, q4 = lane >> 4;
    const int wm = (w >> 1) * 64, wn = (w & 1) * 64;
    const int srow = w * 32 + (lane >> 2);
    const int scol = (lane & 3) * 8;
    const u16* Ab = A + (size_t)(bm * 128 + srow) * DM + scol;
    const u16* Bb = B + (size_t)(bnn * 128 + srow) * DM + scol;
    u16* a_dst = &a_lds[w * 32][0];
    u16* b_dst = &b_lds[w * 32][0];

    f32x4 acc[4][4] = {};

    for (int k0 = 0; k0 < DM; k0 += 32) {
        __syncthreads();
        glds16(Ab + k0,           a_dst);
        glds16(Ab + k0 + 16 * DM, a_dst + 16 * 32);
        glds16(Bb + k0,           b_dst);
        glds16(Bb + k0 + 16 * DM, b_dst + 16 * 32);
        __syncthreads();
        bf16x8 af[4], bf[4];
        #pragma unroll
        for (int rt = 0; rt < 4; rt++)
            af[rt] = *(const bf16x8*)&a_lds[wm + rt * 16 + l15][q4 * 8];
        #pragma unroll
        for (int ct = 0; ct < 4; ct++)
            bf[ct] = *(const bf16x8*)&b_lds[wn + ct * 16 + l15][q4 * 8];
        #pragma unroll
        for (int rt = 0; rt < 4; rt++)
            #pragma unroll
            for (int ct = 0; ct < 4; ct++)
                acc[rt][ct] = __builtin_amdgcn_mfma_f32_16x16x32_bf16(
                    af[rt], bf[ct], acc[rt][ct], 0, 0, 0);
    }

    #pragma unroll
    for (int rt = 0; rt < 4; rt++)
      #pragma unroll
      for (int ct = 0; ct < 4; ct++)
        #pragma unroll
        for (int rg = 0; rg < 4; rg++) {
            const int R = bm * 128 + wm + rt * 16 + q4 * 4 + rg;   // seq*4+b
            const int Cc = bnn * 128 + wn + ct * 16 + l15;         // n*64+d
            const float v = acc[rt][ct][rg];
            const int sq = R >> 2, bb = R & 3, hn = Cc >> 6, dd = Cc & 63;
            const size_t idx = ((size_t)(bb * NH + hn) * SEQ + sq) * DH + dd;
            if (MODE == 1) ((float*)C)[idx] = v;
            else           ((u16*)C)[idx]  = f2bf(v);
        }
}

// ---------------------------------------------------------------------------
// v [b][n][j][d] -> vt [b][n][d][j], 64x64 LDS tile transpose.
// ---------------------------------------------------------------------------
__global__ __launch_bounds__(256) void vtrans_kernel(
    const u16* __restrict__ v_s, u16* __restrict__ vt_s)
{
    __shared__ u16 tl[64][72];
    const int j0 = blockIdx.x * 64;
    const int bn = blockIdx.y;
    const u16* vin = v_s + (size_t)bn * KL * DH;
    u16* vout = vt_s + (size_t)bn * DH * KL;
    const int t = threadIdx.x;
    const int r = t >> 3, c8 = (t & 7) * 8;
    #pragma unroll
    for (int it = 0; it < 64; it += 32)
        *(uint4*)&tl[r + it][c8] = *(const uint4*)(vin + (size_t)(j0 + r + it) * DH + c8);
    __syncthreads();
    #pragma unroll
    for (int it = 0; it < 64; it += 32) {
        const int d = r + it;
        u16 tmp[8];
        #pragma unroll
        for (int jj = 0; jj < 8; jj++) tmp[jj] = tl[c8 + jj][d];
        *(uint4*)&vout[(size_t)d * KL + j0 + c8] = *(const uint4*)tmp;
    }
}

// ---------------------------------------------------------------------------
// Out-projection GEMM (fp32 row-major out), m97-style staging.
// ---------------------------------------------------------------------------
__global__ __launch_bounds__(256) void ogemm_kernel(
    const u16* __restrict__ A, const u16* __restrict__ B,
    float* __restrict__ Cout)
{
    __shared__ u16 a_lds[128][32];
    __shared__ u16 b_lds[128][32];
    const int bm = blockIdx.x, bnn = blockIdx.y;
    const int t = threadIdx.x;
    const int w = t >> 6, lane = t & 63, l15 = lane & 15, q4 = lane >> 4;
    const int wm = (w >> 1) * 64, wn = (w & 1) * 64;
    const int srow = w * 32 + (lane >> 2);
    const int scol = (lane & 3) * 8;
    const u16* Ab = A + (size_t)(bm * 128 + srow) * DM + scol;
    const u16* Bb = B + (size_t)(bnn * 128 + srow) * DM + scol;
    u16* a_dst = &a_lds[w * 32][0];
    u16* b_dst = &b_lds[w * 32][0];

    f32x4 acc[4][4] = {};

    for (int k0 = 0; k0 < DM; k0 += 32) {
        __syncthreads();
        glds16(Ab + k0,           a_dst);
        glds16(Ab + k0 + 16 * DM, a_dst + 16 * 32);
        glds16(Bb + k0,           b_dst);
        glds16(Bb + k0 + 16 * DM, b_dst + 16 * 32);
        __syncthreads();
        bf16x8 af[4], bf[4];
        #pragma unroll
        for (int rt = 0; rt < 4; rt++)
            af[rt] = *(const bf16x8*)&a_lds[wm + rt * 16 + l15][q4 * 8];
        #pragma unroll
        for (int ct = 0; ct < 4; ct++)
            bf[ct] = *(const bf16x8*)&b_lds[wn + ct * 16 + l15][q4 * 8];
        #pragma unroll
        for (int rt = 0; rt < 4; rt++)
            #pragma unroll
            for (int ct = 0; ct < 4; ct++)
                acc[rt][ct] = __builtin_amdgcn_mfma_f32_16x16x32_bf16(
                    af[rt], bf[ct], acc[rt][ct], 0, 0, 0);
    }

    #pragma unroll
    for (int rt = 0; rt < 4; rt++)
      #pragma unroll
      for (int ct = 0; ct < 4; ct++)
        #pragma unroll
        for (int rg = 0; rg < 4; rg++) {
            const int R = bm * 128 + wm + rt * 16 + q4 * 4 + rg;
            const int C = bnn * 128 + wn + ct * 16 + l15;
            Cout[(size_t)R * DM + C] = acc[rt][ct][rg];
        }
}

// ---------------------------------------------------------------------------
// Fused relative attention.  grid = (64 bn, 16 itile) -> block id % 8 ==
// bn % 8: all 16 i-tiles of one (b,n) pin to ONE XCD and share k/vt/kr in
// its L2 (XCD-locality swizzle). 4 waves x 16 q-rows. All tiles staged via
// global_load_lds (round-5 two-barrier structure, separate P scratch).
// l_r cross-lane reduction DEFERRED to epilogue (sum is linear, no running
// max). bd band extract via shfl; masked lanes get p = 0 exactly.
// ---------------------------------------------------------------------------
__global__ __launch_bounds__(256, 3) void attn_kernel(
    const float* __restrict__ q_s, const u16* __restrict__ k_s,
    const u16* __restrict__ vt_s, const u16* __restrict__ kr_s,
    const ulonglong2* __restrict__ pk,
    const float* __restrict__ rwb, const float* __restrict__ rrb,
    const float* __restrict__ rsb, const float* __restrict__ seg_embed,
    u16* __restrict__ av_s)
{
    __shared__ u16 k2[2][64][32];    // [kk-half][j][d32]  (unpadded for glds)
    __shared__ u16 vt2[2][64][32];   // [kk-half][d][j32]
    __shared__ u16 krl[128][64];     // kr rows, seg-swizzled
    __shared__ u16 p_lds[4][16][72];
    __shared__ float e_lds[2][64];

    const int bn = blockIdx.x;           // b*16 + n  (fast dim -> XCD = bn%8)
    const int itile = blockIdx.y;
    const int b = bn >> 4, n = bn & 15;
    const int t = threadIdx.x;
    const int w = t >> 6, lane = t & 63, l15 = lane & 15, q4 = lane >> 4;
    const int i0 = itile * 64;
    const int ib = i0 + w * 16;

    const float* q_bn = q_s + (size_t)bn * QL * DH;
    const u16* k_bn   = k_s  + (size_t)bn * KL * DH;
    const u16* vt_bn  = vt_s + (size_t)bn * DH * KL;
    const u16* kr_bn  = kr_s + (size_t)bn * RL * DH;
    const ulonglong2* pk_b = pk + (size_t)b * QL * JT;

    // ef pre-dots: e_lds[s][block_row] = (q + r_s_bias) . seg_embed[s,n]
    if (t < 128) {
        const int rr = t >> 1, s = t & 1;
        const float* qrow = q_bn + (size_t)(i0 + rr) * DH;
        const float* se = seg_embed + (s * NH + n) * DH;
        const float* bias = rsb + n * DH;
        float acc = 0.f;
        #pragma unroll 16
        for (int d = 0; d < DH; d++) acc += (qrow[d] + bias[d]) * se[d];
        e_lds[s][rr] = acc;
    }

    // q fragments (A-layout: row = l15, k = kk*32 + q4*8 + j), biases folded
    bf16x8 qw[2], qr[2];
    {
        const float* qrow = q_bn + (size_t)(ib + l15) * DH;
        const float* bw = rwb + n * DH;
        const float* br = rrb + n * DH;
        #pragma unroll
        for (int kk = 0; kk < 2; kk++) {
            const int dbase = kk * 32 + q4 * 8;
            #pragma unroll
            for (int j = 0; j < 8; j++) {
                float qv = qrow[dbase + j];
                qw[kk][j] = (short)f2bf(qv + bw[dbase + j]);
                qr[kk][j] = (short)f2bf(qv + br[dbase + j]);
            }
        }
    }

    // k/vt staging lane coords (16 rows per glds, 4 lanes x 16B per row)
    const int srow = lane >> 2;
    const int sseg = (lane & 3) * 8;
    const u16* kg = k_bn  + (size_t)(w * 16 + srow) * DH + sseg;
    const u16* vg = vt_bn + (size_t)(w * 16 + srow) * KL + sseg;
    u16* kd0 = &k2[0][w * 16][0];
    u16* kd1 = &k2[1][w * 16][0];
    u16* vd0 = &vt2[0][w * 16][0];
    u16* vd1 = &vt2[1][w * 16][0];

    // kr staging coords: wave stages rows [w*32, w*32+32) of krl, 4 glds of
    // 8 rows each; seg-XOR swizzle s^(r&7) keeps bd reads at banking floor.
    const int krow = lane >> 3;
    const int ksrcseg = (lane & 7) ^ krow;
    u16* krd = &krl[w * 32][0];

    f32x4 o[4] = {};
    float l_r[4] = {0.f, 0.f, 0.f, 0.f};

    // bd read coords: window wc row = 48 - w*16 + wc*16 + l15; (row&7)==l15&7
    const int lrb = 48 - w * 16 + l15;
    const int sA = ((q4)     ^ (l15 & 7)) * 8;   // kk=0 seg offset (elems)
    const int sB = ((q4 + 4) ^ (l15 & 7)) * 8;   // kk=1

    for (int jt = 0; jt < JT; jt++) {
        const int j0 = jt * 64;
        const int Pbase = j0 + QL - i0 - 63;     // >= 1
        __syncthreads();   // A: prev-tile LDS readers done (e_lds ready @jt=0)
        glds16(kg + (size_t)j0 * DH,      kd0);
        glds16(kg + (size_t)j0 * DH + 32, kd1);
        glds16(vg + j0,                   vd0);
        glds16(vg + j0 + 32,              vd1);
        {
            const u16* krg = kr_bn + (size_t)(Pbase + w * 32 + krow) * DH + ksrcseg * 8;
            #pragma unroll
            for (int m = 0; m < 4; m++)
                glds16(krg + (size_t)m * 8 * DH, krd + m * 8 * 64);
        }
        ulonglong2 mp[4];
        #pragma unroll
        for (int rg = 0; rg < 4; rg++)
            mp[rg] = pk_b[(size_t)(ib + q4 * 4 + rg) * JT + jt];
        __syncthreads();   // B: drains vmcnt -> all LDS tiles ready

        // ---- ac = (q + r_w_bias) . K^T ----
        f32x4 sac[4] = {};
        #pragma unroll
        for (int ct = 0; ct < 4; ct++) {
            bf16x8 kb0 = *(const bf16x8*)&k2[0][ct * 16 + l15][q4 * 8];
            bf16x8 kb1 = *(const bf16x8*)&k2[1][ct * 16 + l15][q4 * 8];
            sac[ct] = __builtin_amdgcn_mfma_f32_16x16x32_bf16(qw[0], kb0, sac[ct], 0, 0, 0);
            sac[ct] = __builtin_amdgcn_mfma_f32_16x16x32_bf16(qw[1], kb1, sac[ct], 0, 0, 0);
        }

        // ---- bd window MFMAs (B-frags from swizzled krl) ----
        f32x4 bacc[5] = {};
        #pragma unroll
        for (int wc = 0; wc < 5; wc++) {
            bf16x8 b0 = *(const bf16x8*)&krl[lrb + wc * 16][sA];
            bf16x8 b1 = *(const bf16x8*)&krl[lrb + wc * 16][sB];
            bacc[wc] = __builtin_amdgcn_mfma_f32_16x16x32_bf16(qr[0], b0, bacc[wc], 0, 0, 0);
            bacc[wc] = __builtin_amdgcn_mfma_f32_16x16x32_bf16(qr[1], b1, bacc[wc], 0, 0, 0);
        }

        // ---- band extract (shfl) + scores + exp + P-store; l_r stays
        //      per-lane partial (quad reduction deferred to epilogue) ----
        #pragma unroll
        for (int rg = 0; rg < 4; rg++) {
            const int row = q4 * 4 + rg;
            const int v = l15 + 15 - row;          // in [0,30]
            const int srcl = (q4 << 4) | (v & 15);
            float sh[5];
            #pragma unroll
            for (int w5 = 0; w5 < 5; w5++)
                sh[w5] = __shfl(bacc[w5][rg], srcl, 64);
            const float e0 = e_lds[0][w * 16 + row];
            const float e1 = e_lds[1][w * 16 + row];
            float s0 = 0.f;
            #pragma unroll
            for (int ct = 0; ct < 4; ct++) {
                const float bd = (v < 16) ? sh[ct] : sh[ct + 1];
                const int bit = ct * 16 + l15;
                const float ef = ((mp[rg].y >> bit) & 1ull) ? e1 : e0;
                const float s = (sac[ct][rg] + bd + ef) * SCALE;
                float p = __expf(s);
                p = ((mp[rg].x >> bit) & 1ull) ? 0.f : p;   // exact zero
                p_lds[w][row][ct * 16 + l15] = f2bf(p);
                s0 += p;
            }
            l_r[rg] += s0;
        }

        // ---- PV MFMA (P read back in A-layout, same wave) ----
        #pragma unroll
        for (int kk = 0; kk < 2; kk++) {
            bf16x8 pf = *(const bf16x8*)&p_lds[w][l15][kk * 32 + q4 * 8];
            #pragma unroll
            for (int dt = 0; dt < 4; dt++) {
                bf16x8 vf = *(const bf16x8*)&vt2[kk][dt * 16 + l15][q4 * 8];
                o[dt] = __builtin_amdgcn_mfma_f32_16x16x32_bf16(pf, vf, o[dt], 0, 0, 0);
            }
        }
    }

    // ---- epilogue: quad-reduce l_r once, normalize, write attn_vec ----
    #pragma unroll
    for (int rg = 0; rg < 4; rg++) {
        #pragma unroll
        for (int off = 1; off < 16; off <<= 1)
            l_r[rg] += __shfl_xor(l_r[rg], off, 64);
        l_r[rg] = 1.f / l_r[rg];
    }
    #pragma unroll
    for (int dt = 0; dt < 4; dt++)
        #pragma unroll
        for (int rg = 0; rg < 4; rg++) {
            const int row = q4 * 4 + rg;
            const int ii = ib + row;
            const int d = dt * 16 + l15;
            const float v = o[dt][rg] * l_r[rg];
            av_s[(size_t)(ii * BS + b) * DM + n * DH + d] = f2bf(v);
        }
}

// ---------------------------------------------------------------------------
// Residual + LayerNorm: out = LN(ao + h) * gamma + beta. One block per row.
// ---------------------------------------------------------------------------
__global__ __launch_bounds__(256) void ln_kernel(
    const float* __restrict__ ao, const float* __restrict__ h,
    const float* __restrict__ gamma, const float* __restrict__ beta,
    float* __restrict__ out)
{
    __shared__ float red[8];
    const int row = blockIdx.x, t = threadIdx.x;
    const float* a  = ao + (size_t)row * DM;
    const float* hh = h  + (size_t)row * DM;
    float4 av = *(const float4*)(a + t * 4);
    float4 hv = *(const float4*)(hh + t * 4);
    const float x0 = av.x + hv.x, x1 = av.y + hv.y;
    const float x2 = av.z + hv.z, x3 = av.w + hv.w;
    float s = x0 + x1 + x2 + x3;
    float s2 = x0 * x0 + x1 * x1 + x2 * x2 + x3 * x3;
    #pragma unroll
    for (int off = 1; off < 64; off <<= 1) {
        s  += __shfl_xor(s, off, 64);
        s2 += __shfl_xor(s2, off, 64);
    }
    const int w = t >> 6;
    if ((t & 63) == 0) { red[w] = s; red[4 + w] = s2; }
    __syncthreads();
    s  = red[0] + red[1] + red[2] + red[3];
    s2 = red[4] + red[5] + red[6] + red[7];
    const float mu = s * (1.f / DM);
    const float var = s2 * (1.f / DM) - mu * mu;
    const float rstd = rsqrtf(var + 1e-12f);
    float4 g  = *(const float4*)(gamma + t * 4);
    float4 bb = *(const float4*)(beta + t * 4);
    float4 ov;
    ov.x = (x0 - mu) * rstd * g.x + bb.x;
    ov.y = (x1 - mu) * rstd * g.y + bb.y;
    ov.z = (x2 - mu) * rstd * g.z + bb.z;
    ov.w = (x3 - mu) * rstd * g.w + bb.w;
    *(float4*)(out + (size_t)row * DM + t * 4) = ov;
}

// ---------------------------------------------------------------------------
extern "C" void kernel_launch(void* const* d_in, const int* in_sizes, int n_in,
                              void* d_out, int out_size, void* d_ws, size_t ws_size,
                              hipStream_t stream) {
    (void)in_sizes; (void)n_in; (void)out_size; (void)ws_size;
    const float* h    = (const float*)d_in[0];
    const float* r    = (const float*)d_in[1];
    const float* mems = (const float*)d_in[2];
    const float* mask = (const float*)d_in[3];
    const float* segm = (const float*)d_in[4];
    const float* Wq   = (const float*)d_in[5];
    const float* Wk   = (const float*)d_in[6];
    const float* Wv   = (const float*)d_in[7];
    const float* Wo   = (const float*)d_in[8];
    const float* Wr   = (const float*)d_in[9];
    const float* rwb  = (const float*)d_in[10];
    const float* rrb  = (const float*)d_in[11];
    const float* rsb  = (const float*)d_in[12];
    const float* semb = (const float*)d_in[13];
    const float* gam  = (const float*)d_in[14];
    const float* bet  = (const float*)d_in[15];
    float* out = (float*)d_out;

    char* wsb = (char*)d_ws;
    size_t off = 0;
    auto alloc = [&](size_t bytes) -> void* {
        void* p = wsb + off; off += (bytes + 255) & ~(size_t)255; return p;
    };
    u16* catb = (u16*)alloc((size_t)KL * BS * DM * 2);
    u16* rb   = (u16*)alloc((size_t)RL * BS * DM * 2);
    u16* WqT  = (u16*)alloc((size_t)DM * DM * 2);
    u16* WkT  = (u16*)alloc((size_t)DM * DM * 2);
    u16* WvT  = (u16*)alloc((size_t)DM * DM * 2);
    u16* WrT  = (u16*)alloc((size_t)DM * DM * 2);
    u16* WoB  = (u16*)alloc((size_t)DM * DM * 2);
    float* q_s = (float*)alloc((size_t)BS * NH * QL * DH * 4);
    u16* k_s  = (u16*)alloc((size_t)BS * NH * KL * DH * 2);
    u16* vt_s = (u16*)alloc((size_t)BS * NH * KL * DH * 2);
    u16* kr_s = (u16*)alloc((size_t)BS * NH * RL * DH * 2 + 8192); // tail pad: kr window over-read
    u16* av_s = (u16*)alloc((size_t)QL * BS * DM * 2);
    float* ao_s = (float*)alloc((size_t)QL * BS * DM * 4);
    ulonglong2* pk = (ulonglong2*)alloc((size_t)BS * QL * JT * 16);
    u16* v_s = (u16*)ao_s;   // alias: v_s dead before ao_s is written

    // 1) fused prep: convert + W transpose + mask/seg pack (one launch)
    prep_kernel<<<43008, 256, 0, stream>>>(mems, h, r, Wo, mask, segm,
                                           Wq, Wk, Wv, Wr,
                                           catb, rb, WoB,
                                           WqT, WkT, WvT, WrT, pk);
    // 2) all 4 projections in one launch (hb = h part of catb)
    const u16* hb = catb + (size_t)2048 * DM;
    proj_kernel<<<1664, 256, 0, stream>>>(hb, catb, rb, WqT, WkT, WvT, WrT,
                                          q_s, k_s, v_s, kr_s);
    // 2b) v -> v^T
    vtrans_kernel<<<dim3(JT, 64), 256, 0, stream>>>(v_s, vt_s);
    // 3) fused attention — grid (bn, itile): XCD = bn%8 locality swizzle
    attn_kernel<<<dim3(64, 16), 256, 0, stream>>>(q_s, k_s, vt_s, kr_s, pk,
                                                  rwb, rrb, rsb, semb, av_s);
    // 4) output projection + residual layernorm
    ogemm_kernel<<<dim3(32, 8), 256, 0, stream>>>(av_s, WoB, ao_s);
    ln_kernel<<<4096, 256, 0, stream>>>(ao_s, h, gam, bet, out);
}